// Round 2
// baseline (320.052 us; speedup 1.0000x reference)
//
#include <hip/hip_runtime.h>

#define F 128
#define TILE 32
#define GRIDN 512
#define NTHR 512

typedef __attribute__((ext_vector_type(8))) __bf16 bf16x8;
typedef __attribute__((ext_vector_type(4))) float f32x4;
typedef __attribute__((ext_vector_type(8))) unsigned short us8;
typedef __attribute__((ext_vector_type(4))) unsigned short us4;
typedef __attribute__((ext_vector_type(2))) unsigned short us2;

__device__ __forceinline__ unsigned short f2bf(float x) {
    unsigned u = __builtin_bit_cast(unsigned, x);
    u = u + 0x7FFFu + ((u >> 16) & 1u);   // RNE
    return (unsigned short)(u >> 16);
}
__device__ __forceinline__ float bf2f(unsigned short u) {
    unsigned x = ((unsigned)u) << 16;
    return __builtin_bit_cast(float, x);
}
__device__ __forceinline__ bf16x8 pack8(float4 a, float4 b) {
    us8 t;
    t[0] = f2bf(a.x); t[1] = f2bf(a.y); t[2] = f2bf(a.z); t[3] = f2bf(a.w);
    t[4] = f2bf(b.x); t[5] = f2bf(b.y); t[6] = f2bf(b.z); t[7] = f2bf(b.w);
    return __builtin_bit_cast(bf16x8, t);
}

// LDS map (ushort units), total 38912 shorts = 77824 B (2 blocks/CU):
//  A1 buf0: [0,13056)      96 rows (m=c*32+nl) x 136   (v tile bf16)
//  A1 buf1: [13056,26112)
//  A2:      [26112,34560)  32 rows x 264  (s bf16 | ||Vv||^2 bf16)
//  A3:      [34560,38912)  32 rows x 136  (h bf16)
#define A1S 136
#define A2S 264
#define A2B 26112
#define A3B 34560

__global__ __launch_bounds__(NTHR, 4)
void painn_fused(const float* __restrict__ s, const float* __restrict__ v,
                 const float* __restrict__ Uw, const float* __restrict__ Vw,
                 const float* __restrict__ aw1, const float* __restrict__ ab1,
                 const float* __restrict__ aw2, const float* __restrict__ ab2,
                 float* __restrict__ out, int Ntot)
{
    __shared__ unsigned short SH[38912];

    const int tid  = threadIdx.x;
    const int lane = tid & 63;
    const int w    = tid >> 6;        // wave 0..7
    const int l15  = lane & 15;
    const int kp   = lane >> 4;       // 0..3
    const int col  = (w << 4) | l15;  // output column 0..127
    const size_t NF = (size_t)Ntot * F;
    const int NT   = (Ntot + TILE - 1) / TILE;

    const float b1  = ab1[col];
    const float bss = ab2[col];
    const float bsv = ab2[F + col];
    const float bvv = ab2[2 * F + col];

    const int vf0  = lane << 1;          // f-pair this lane stages for v
    const int srow = tid >> 4;           // s staging row 0..31
    const int sf0  = (tid & 15) << 3;    // s staging f-offset

    int t = blockIdx.x;
    int cur = 0;
    us4 sreg[2];   // s[t] tile, bf16, carried into A2 write

    // ---------------- prologue: stage tile t into A1[0], s into sreg ----------------
    if (t < NT) {
        #pragma unroll
        for (int it = 0; it < 4; ++it) {
            int nl = w + (it << 3);
            int n  = t * TILE + nl; if (n >= Ntot) n = Ntot - 1;
            const float* src = v + ((size_t)n * F + vf0) * 3;
            float2 ab = *(const float2*)(src);
            float2 cd = *(const float2*)(src + 2);
            float2 ef = *(const float2*)(src + 4);
            us2 p;
            p[0] = f2bf(ab.x); p[1] = f2bf(cd.y); *(us2*)&SH[(0 * TILE + nl) * A1S + vf0] = p;
            p[0] = f2bf(ab.y); p[1] = f2bf(ef.x); *(us2*)&SH[(1 * TILE + nl) * A1S + vf0] = p;
            p[0] = f2bf(cd.x); p[1] = f2bf(ef.y); *(us2*)&SH[(2 * TILE + nl) * A1S + vf0] = p;
        }
        {
            int n = t * TILE + srow; if (n >= Ntot) n = Ntot - 1;
            const float4* p = (const float4*)&s[(size_t)n * F + sf0];
            float4 x = p[0], y = p[1];
            us4 t0, t1;
            t0[0] = f2bf(x.x); t0[1] = f2bf(x.y); t0[2] = f2bf(x.z); t0[3] = f2bf(x.w);
            t1[0] = f2bf(y.x); t1[1] = f2bf(y.y); t1[2] = f2bf(y.z); t1[3] = f2bf(y.w);
            sreg[0] = t0; sreg[1] = t1;
        }
    }

    for (; t < NT; t += GRIDN) {
        const bool hasnext = (t + GRIDN) < NT;
        const int a1c = cur ? 13056 : 0;
        const int a1n = cur ? 0 : 13056;
        __syncthreads();   // A1[cur] + sreg staged (prologue or previous iteration)

        // ---- JIT-convert U,V weight fragments (L2-hot) ----
        bf16x8 bU[4], bV[4];
        #pragma unroll
        for (int ks = 0; ks < 4; ++ks) {
            int k0 = (ks << 5) + (kp << 3);
            const float4* pu = (const float4*)&Uw[col * F + k0];
            bU[ks] = pack8(pu[0], pu[1]);
            const float4* pv = (const float4*)&Vw[col * F + k0];
            bV[ks] = pack8(pv[0], pv[1]);
        }

        // ---- stage 1: Uv, Vv (48 MFMAs/wave) ----
        f32x4 accU[6], accV[6];
        #pragma unroll
        for (int i = 0; i < 6; ++i) { accU[i] = (f32x4){0.f,0.f,0.f,0.f}; accV[i] = (f32x4){0.f,0.f,0.f,0.f}; }
        #pragma unroll
        for (int ks = 0; ks < 4; ++ks) {
            #pragma unroll
            for (int mt = 0; mt < 6; ++mt) {   // mt = c*2+nt
                bf16x8 a = *(const bf16x8*)&SH[a1c + (mt * 16 + l15) * A1S + (ks << 5) + (kp << 3)];
                accU[mt] = __builtin_amdgcn_mfma_f32_16x16x32_bf16(a, bU[ks], accU[mt], 0, 0, 0);
                accV[mt] = __builtin_amdgcn_mfma_f32_16x16x32_bf16(a, bV[ks], accV[mt], 0, 0, 0);
            }
        }

        // ---- norms, inner products; pack Uv to bf16 ----
        float nrmv[2][4], inr[2][4];
        us4 pU[6];
        #pragma unroll
        for (int nt = 0; nt < 2; ++nt) {
            #pragma unroll
            for (int r = 0; r < 4; ++r) {
                float vn = 0.f, in = 0.f;
                #pragma unroll
                for (int c = 0; c < 3; ++c) {
                    float uu = accU[c * 2 + nt][r];
                    float vv = accV[c * 2 + nt][r];
                    vn += vv * vv;
                    in += uu * vv;
                }
                nrmv[nt][r] = vn;
                inr[nt][r]  = in;
            }
        }
        #pragma unroll
        for (int mt = 0; mt < 6; ++mt) {
            us4 q;
            q[0] = f2bf(accU[mt][0]); q[1] = f2bf(accU[mt][1]);
            q[2] = f2bf(accU[mt][2]); q[3] = f2bf(accU[mt][3]);
            pU[mt] = q;
        }

        // ---- issue next-tile prefetch (raw f32 regs; converted after B1) ----
        float2 vpre[12];
        float4 spre[2];
        if (hasnext) {
            int t2 = t + GRIDN;
            #pragma unroll
            for (int it = 0; it < 4; ++it) {
                int nl = w + (it << 3);
                int n  = t2 * TILE + nl; if (n >= Ntot) n = Ntot - 1;
                const float* src = v + ((size_t)n * F + vf0) * 3;
                vpre[it * 3 + 0] = *(const float2*)(src);
                vpre[it * 3 + 1] = *(const float2*)(src + 2);
                vpre[it * 3 + 2] = *(const float2*)(src + 4);
            }
            int n = t2 * TILE + srow; if (n >= Ntot) n = Ntot - 1;
            const float4* p = (const float4*)&s[(size_t)n * F + sf0];
            spre[0] = p[0]; spre[1] = p[1];
        }

        // ---- A2 staging: s (from sreg) + ||Vv||^2 ----
        *(us4*)&SH[A2B + srow * A2S + sf0]     = sreg[0];
        *(us4*)&SH[A2B + srow * A2S + sf0 + 4] = sreg[1];
        #pragma unroll
        for (int nt = 0; nt < 2; ++nt) {
            #pragma unroll
            for (int r = 0; r < 4; ++r) {
                int row = nt * 16 + (kp << 2) + r;
                SH[A2B + row * A2S + 128 + col] = f2bf(nrmv[nt][r]);
            }
        }
        __syncthreads();   // B1: A2 ready; A1[cur] stage-1 reads done

        // ---- convert prefetch -> A1[next], sreg (vmcnt wait lands here) ----
        if (hasnext) {
            #pragma unroll
            for (int it = 0; it < 4; ++it) {
                int nl = w + (it << 3);
                float2 ab = vpre[it * 3 + 0];
                float2 cd = vpre[it * 3 + 1];
                float2 ef = vpre[it * 3 + 2];
                us2 p;
                p[0] = f2bf(ab.x); p[1] = f2bf(cd.y); *(us2*)&SH[a1n + (0 * TILE + nl) * A1S + vf0] = p;
                p[0] = f2bf(ab.y); p[1] = f2bf(ef.x); *(us2*)&SH[a1n + (1 * TILE + nl) * A1S + vf0] = p;
                p[0] = f2bf(cd.x); p[1] = f2bf(ef.y); *(us2*)&SH[a1n + (2 * TILE + nl) * A1S + vf0] = p;
            }
            us4 t0, t1;
            t0[0] = f2bf(spre[0].x); t0[1] = f2bf(spre[0].y); t0[2] = f2bf(spre[0].z); t0[3] = f2bf(spre[0].w);
            t1[0] = f2bf(spre[1].x); t1[1] = f2bf(spre[1].y); t1[2] = f2bf(spre[1].z); t1[3] = f2bf(spre[1].w);
            sreg[0] = t0; sreg[1] = t1;
        }

        // ---- stage 2: h = ssp(mlp_in @ w1.T + b1)  (16 MFMAs/wave, JIT weights) ----
        f32x4 accH[2];
        accH[0] = (f32x4){0.f,0.f,0.f,0.f}; accH[1] = (f32x4){0.f,0.f,0.f,0.f};
        #pragma unroll
        for (int ks = 0; ks < 8; ++ks) {
            int k0 = (ks << 5) + (kp << 3);
            const float4* p = (const float4*)&aw1[col * 256 + k0];
            bf16x8 bw = pack8(p[0], p[1]);
            #pragma unroll
            for (int nt = 0; nt < 2; ++nt) {
                bf16x8 a = *(const bf16x8*)&SH[A2B + (nt * 16 + l15) * A2S + k0];
                accH[nt] = __builtin_amdgcn_mfma_f32_16x16x32_bf16(a, bw, accH[nt], 0, 0, 0);
            }
        }
        #pragma unroll
        for (int nt = 0; nt < 2; ++nt) {
            #pragma unroll
            for (int r = 0; r < 4; ++r) {
                float x = accH[nt][r] + b1;
                float hsp = fmaxf(x, 0.f) + __logf(1.f + __expf(-fabsf(x))) - 0.69314718056f;
                int row = nt * 16 + (kp << 2) + r;
                SH[A3B + row * A1S + col] = f2bf(hsp);
            }
        }
        __syncthreads();   // B2: A3 ready

        // ---- stage 3: a = h @ w2.T + b2 (3 GEMMs fused in one k-loop) ----
        f32x4 accA[2], accS[2], accT[2];
        #pragma unroll
        for (int i = 0; i < 2; ++i) {
            accA[i] = (f32x4){0.f,0.f,0.f,0.f};
            accS[i] = (f32x4){0.f,0.f,0.f,0.f};
            accT[i] = (f32x4){0.f,0.f,0.f,0.f};
        }
        #pragma unroll
        for (int ks = 0; ks < 4; ++ks) {
            int k0 = (ks << 5) + (kp << 3);
            const float4* p0 = (const float4*)&aw2[(size_t)(0 * F + col) * F + k0];
            const float4* p1 = (const float4*)&aw2[(size_t)(1 * F + col) * F + k0];
            const float4* p2 = (const float4*)&aw2[(size_t)(2 * F + col) * F + k0];
            bf16x8 bws = pack8(p0[0], p0[1]);
            bf16x8 bwt = pack8(p1[0], p1[1]);
            bf16x8 bwv = pack8(p2[0], p2[1]);
            #pragma unroll
            for (int nt = 0; nt < 2; ++nt) {
                bf16x8 a = *(const bf16x8*)&SH[A3B + (nt * 16 + l15) * A1S + k0];
                accS[nt] = __builtin_amdgcn_mfma_f32_16x16x32_bf16(a, bws, accS[nt], 0, 0, 0);
                accT[nt] = __builtin_amdgcn_mfma_f32_16x16x32_bf16(a, bwt, accT[nt], 0, 0, 0);
                accA[nt] = __builtin_amdgcn_mfma_f32_16x16x32_bf16(a, bwv, accA[nt], 0, 0, 0);
            }
        }

        // ---- epilogue: v_new then s_new (residuals from LDS bf16) ----
        #pragma unroll
        for (int nt = 0; nt < 2; ++nt) {
            #pragma unroll
            for (int r = 0; r < 4; ++r) {
                int nl = nt * 16 + (kp << 2) + r;
                int n  = t * TILE + nl;
                if (n < Ntot) {
                    float avv = accA[nt][r] + bvv;
                    size_t base = ((size_t)n * F + col) * 3;
                    #pragma unroll
                    for (int c = 0; c < 3; ++c) {
                        float vres = bf2f(SH[a1c + (c * TILE + nl) * A1S + col]);
                        float uv   = bf2f(pU[c * 2 + nt][r]);
                        out[NF + base + c] = vres + avv * uv;
                    }
                    float sres = bf2f(SH[A2B + nl * A2S + col]);
                    float a_ss = accS[nt][r] + bss;
                    float a_sv = accT[nt][r] + bsv;
                    out[(size_t)n * F + col] = sres + a_ss + a_sv * inr[nt][r];
                }
            }
        }
        cur ^= 1;
    }
}

extern "C" void kernel_launch(void* const* d_in, const int* in_sizes, int n_in,
                              void* d_out, int out_size, void* d_ws, size_t ws_size,
                              hipStream_t stream) {
    (void)n_in; (void)d_ws; (void)ws_size; (void)out_size;
    const float* s   = (const float*)d_in[0];
    const float* v   = (const float*)d_in[1];
    const float* Uw  = (const float*)d_in[2];
    const float* Vw  = (const float*)d_in[3];
    const float* aw1 = (const float*)d_in[4];
    const float* ab1 = (const float*)d_in[5];
    const float* aw2 = (const float*)d_in[6];
    const float* ab2 = (const float*)d_in[7];
    float* out = (float*)d_out;
    int Ntot = in_sizes[0] / F;                 // 100000
    hipLaunchKernelGGL(painn_fused, dim3(GRIDN), dim3(NTHR), 0, stream,
                       s, v, Uw, Vw, aw1, ab1, aw2, ab2, out, Ntot);
}

// Round 3
// 182.190 us; speedup vs baseline: 1.7567x; 1.7567x over previous
//
#include <hip/hip_runtime.h>

#define F 128
#define TILE 32
#define NTHR 512
#define NBLK 256

typedef __attribute__((ext_vector_type(8))) __bf16 bf16x8;
typedef __attribute__((ext_vector_type(4))) float f32x4;
typedef __attribute__((ext_vector_type(8))) unsigned short us8;
typedef __attribute__((ext_vector_type(4))) unsigned short us4;
typedef __attribute__((ext_vector_type(2))) unsigned short us2;

__device__ __forceinline__ unsigned short f2bf(float x) {
    __bf16 h = (__bf16)x;                       // HW v_cvt (RNE)
    return __builtin_bit_cast(unsigned short, h);
}
__device__ __forceinline__ float bf2f(unsigned short u) {
    unsigned x = ((unsigned)u) << 16;
    return __builtin_bit_cast(float, x);
}
__device__ __forceinline__ bf16x8 pack8(float4 a, float4 b) {
    us8 t;
    t[0] = f2bf(a.x); t[1] = f2bf(a.y); t[2] = f2bf(a.z); t[3] = f2bf(a.w);
    t[4] = f2bf(b.x); t[5] = f2bf(b.y); t[6] = f2bf(b.z); t[7] = f2bf(b.w);
    return __builtin_bit_cast(bf16x8, t);
}

// async global->LDS, 16B per lane; lds base must be wave-uniform
__device__ __forceinline__ void gload16(const float* g, const unsigned short* l) {
    __builtin_amdgcn_global_load_lds(
        (const __attribute__((address_space(1))) void*)g,
        (__attribute__((address_space(3))) void*)l, 16, 0, 0);
}
// barrier with LDS-only drain: async global_load_lds stays in flight
__device__ __forceinline__ void bar_lgkm() {
    asm volatile("s_waitcnt lgkmcnt(0)" ::: "memory");
    __builtin_amdgcn_s_barrier();
}
// full drain barrier (loop top: raw tile must be complete)
__device__ __forceinline__ void bar_full() {
    asm volatile("s_waitcnt vmcnt(0) lgkmcnt(0)" ::: "memory");
    __builtin_amdgcn_s_barrier();
}

// LDS map (ushort units), total 58624 shorts = 117248 B -> 1 block/CU
#define RAWV 0        // 24576 sh = 49152 B : raw f32 v tile (32x128x3), linear
#define RAWS 24576    // 8192 sh  = 16384 B : raw f32 s tile (32x128), linear
#define A1B  32768    // 96 x 136 : v bf16, row m = c*32+nl
#define A1S  136
#define A2B  45824    // 32 x 264 : s bf16 | ||Vv||^2 bf16
#define A2S  264
#define A3B  54272    // 32 x 136 : h bf16
#define A3S  136
#define SHSZ 58624

template<bool PRE>
__device__ __forceinline__ bf16x8 ldw8(const unsigned short* wbf, const float* wf, int idx) {
    if constexpr (PRE) {
        return *(const bf16x8*)&wbf[idx];
    } else {
        const float4* p = (const float4*)&wf[idx];
        return pack8(p[0], p[1]);
    }
}

__global__ __launch_bounds__(256)
void prep_w(const float* __restrict__ Uw, const float* __restrict__ Vw,
            const float* __restrict__ aw1, const float* __restrict__ aw2,
            unsigned short* __restrict__ wbf)
{
    int i = (blockIdx.x * 256 + threadIdx.x) * 4;   // 0..114684, grid 112x256
    const float* src; int off;
    if (i < 16384)      { src = Uw;  off = i; }
    else if (i < 32768) { src = Vw;  off = i - 16384; }
    else if (i < 65536) { src = aw1; off = i - 32768; }
    else                { src = aw2; off = i - 65536; }
    float4 x = *(const float4*)&src[off];
    us4 o;
    o[0] = f2bf(x.x); o[1] = f2bf(x.y); o[2] = f2bf(x.z); o[3] = f2bf(x.w);
    *(us4*)&wbf[i] = o;
}

template<bool PRE>
__global__ __launch_bounds__(NTHR, 2)
void painn_main(const float* __restrict__ s, const float* __restrict__ v,
                const float* __restrict__ Uw, const float* __restrict__ Vw,
                const float* __restrict__ aw1, const float* __restrict__ ab1,
                const float* __restrict__ aw2, const float* __restrict__ ab2,
                const unsigned short* __restrict__ wbf,
                float* __restrict__ out, int Ntot)
{
    __shared__ __align__(16) unsigned short SH[SHSZ];

    const int tid  = threadIdx.x;
    const int lane = tid & 63;
    const int w    = tid >> 6;        // wave 0..7
    const int l15  = lane & 15;
    const int kp   = lane >> 4;       // 0..3
    const int col  = (w << 4) | l15;  // output column 0..127
    const size_t NF = (size_t)Ntot * F;
    const int NT   = Ntot / TILE;     // exact: 100000/32 = 3125

    const unsigned short* wU  = wbf;
    const unsigned short* wV  = wbf + 16384;
    const unsigned short* wW1 = wbf + 32768;
    const unsigned short* wW2 = wbf + 65536;

    const float b1  = ab1[col];
    const float bss = ab2[col];
    const float bsv = ab2[F + col];
    const float bvv = ab2[2 * F + col];

    const int vf0  = lane << 1;          // f-pair this lane converts for v
    const int srow = tid >> 4;           // s row 0..31
    const int sf0  = (tid & 15) << 3;    // s f-offset (8 floats)

    const float* rawv = (const float*)&SH[RAWV];
    const float* raws = (const float*)&SH[RAWS];

    // ---- prologue: issue async loads for first tile ----
    {
        int t0 = blockIdx.x;
        const float* vsrc = v + (size_t)t0 * TILE * 384;
        const float* ssrc = s + (size_t)t0 * TILE * 128;
        #pragma unroll
        for (int j = 0; j < 6; ++j) {
            int ofs = (w + j * 8) * 256;                 // floats, 1024B/wave-round
            gload16(vsrc + ofs + lane * 4, &SH[RAWV + ofs * 2]);
        }
        #pragma unroll
        for (int j = 0; j < 2; ++j) {
            int ofs = (w + j * 8) * 256;
            gload16(ssrc + ofs + lane * 4, &SH[RAWS + ofs * 2]);
        }
    }

    for (int t = blockIdx.x; t < NT; t += NBLK) {
        bar_full();   // raw tile complete; prev iter LDS reads done

        // ---- convert: raw f32 -> A1 (v bf16, c-major rows) + A2 s-half ----
        #pragma unroll
        for (int it = 0; it < 4; ++it) {
            int nl = w + (it << 3);
            const float2* src = (const float2*)&rawv[nl * 384 + vf0 * 3];
            float2 ab = src[0], cd = src[1], ef = src[2];
            us2 p;
            p[0] = f2bf(ab.x); p[1] = f2bf(cd.y); *(us2*)&SH[A1B + (0 * TILE + nl) * A1S + vf0] = p;
            p[0] = f2bf(ab.y); p[1] = f2bf(ef.x); *(us2*)&SH[A1B + (1 * TILE + nl) * A1S + vf0] = p;
            p[0] = f2bf(cd.x); p[1] = f2bf(ef.y); *(us2*)&SH[A1B + (2 * TILE + nl) * A1S + vf0] = p;
        }
        {
            const float4* sp = (const float4*)&raws[srow * 128 + sf0];
            float4 x = sp[0], y = sp[1];
            us4 t0, t1;
            t0[0] = f2bf(x.x); t0[1] = f2bf(x.y); t0[2] = f2bf(x.z); t0[3] = f2bf(x.w);
            t1[0] = f2bf(y.x); t1[1] = f2bf(y.y); t1[2] = f2bf(y.z); t1[3] = f2bf(y.w);
            *(us4*)&SH[A2B + srow * A2S + sf0]     = t0;
            *(us4*)&SH[A2B + srow * A2S + sf0 + 4] = t1;
        }
        bar_lgkm();   // raw reads done; A1/A2-s visible. vmcnt NOT drained.

        // ---- issue async loads for next tile into raw (fire-and-forget) ----
        if (t + NBLK < NT) {
            int t2 = t + NBLK;
            const float* vsrc = v + (size_t)t2 * TILE * 384;
            const float* ssrc = s + (size_t)t2 * TILE * 128;
            #pragma unroll
            for (int j = 0; j < 6; ++j) {
                int ofs = (w + j * 8) * 256;
                gload16(vsrc + ofs + lane * 4, &SH[RAWV + ofs * 2]);
            }
            #pragma unroll
            for (int j = 0; j < 2; ++j) {
                int ofs = (w + j * 8) * 256;
                gload16(ssrc + ofs + lane * 4, &SH[RAWS + ofs * 2]);
            }
        }

        // ---- stage 1: Uv, Vv (48 MFMAs/wave) ----
        bf16x8 bU[4], bV[4];
        #pragma unroll
        for (int ks = 0; ks < 4; ++ks) {
            int k0 = (ks << 5) + (kp << 3);
            bU[ks] = ldw8<PRE>(wU, Uw, col * F + k0);
            bV[ks] = ldw8<PRE>(wV, Vw, col * F + k0);
        }
        f32x4 accU[6], accV[6];
        #pragma unroll
        for (int i = 0; i < 6; ++i) { accU[i] = (f32x4){0.f,0.f,0.f,0.f}; accV[i] = (f32x4){0.f,0.f,0.f,0.f}; }
        #pragma unroll
        for (int ks = 0; ks < 4; ++ks) {
            #pragma unroll
            for (int mt = 0; mt < 6; ++mt) {   // mt = c*2+nt
                bf16x8 a = *(const bf16x8*)&SH[A1B + (mt * 16 + l15) * A1S + (ks << 5) + (kp << 3)];
                accU[mt] = __builtin_amdgcn_mfma_f32_16x16x32_bf16(a, bU[ks], accU[mt], 0, 0, 0);
                accV[mt] = __builtin_amdgcn_mfma_f32_16x16x32_bf16(a, bV[ks], accV[mt], 0, 0, 0);
            }
        }

        // ---- norms / inner products; pack Uv to bf16 ----
        float inr[2][4];
        us4 pU[6];
        #pragma unroll
        for (int nt = 0; nt < 2; ++nt) {
            #pragma unroll
            for (int r = 0; r < 4; ++r) {
                float vn = 0.f, in = 0.f;
                #pragma unroll
                for (int c = 0; c < 3; ++c) {
                    float uu = accU[c * 2 + nt][r];
                    float vv = accV[c * 2 + nt][r];
                    vn += vv * vv;
                    in += uu * vv;
                }
                inr[nt][r] = in;
                int row = nt * 16 + (kp << 2) + r;
                SH[A2B + row * A2S + 128 + col] = f2bf(vn);
            }
        }
        #pragma unroll
        for (int mt = 0; mt < 6; ++mt) {
            us4 q;
            q[0] = f2bf(accU[mt][0]); q[1] = f2bf(accU[mt][1]);
            q[2] = f2bf(accU[mt][2]); q[3] = f2bf(accU[mt][3]);
            pU[mt] = q;
        }
        bar_lgkm();   // A2 nrm-half visible

        // ---- stage 2: h = shifted_softplus(mlp_in @ w1.T + b1) ----
        f32x4 accH[2];
        accH[0] = (f32x4){0.f,0.f,0.f,0.f}; accH[1] = (f32x4){0.f,0.f,0.f,0.f};
        #pragma unroll
        for (int ks = 0; ks < 8; ++ks) {
            int k0 = (ks << 5) + (kp << 3);
            bf16x8 bw = ldw8<PRE>(wW1, aw1, col * 256 + k0);
            #pragma unroll
            for (int nt = 0; nt < 2; ++nt) {
                bf16x8 a = *(const bf16x8*)&SH[A2B + (nt * 16 + l15) * A2S + k0];
                accH[nt] = __builtin_amdgcn_mfma_f32_16x16x32_bf16(a, bw, accH[nt], 0, 0, 0);
            }
        }
        #pragma unroll
        for (int nt = 0; nt < 2; ++nt) {
            #pragma unroll
            for (int r = 0; r < 4; ++r) {
                float x = accH[nt][r] + b1;
                float hsp = fmaxf(x, 0.f) + __logf(1.f + __expf(-fabsf(x))) - 0.69314718056f;
                int row = nt * 16 + (kp << 2) + r;
                SH[A3B + row * A3S + col] = f2bf(hsp);
            }
        }
        bar_lgkm();   // A3 visible

        // ---- stage 3: three output GEMMs in one k-loop ----
        f32x4 accA[2], accS[2], accT[2];
        #pragma unroll
        for (int i = 0; i < 2; ++i) {
            accA[i] = (f32x4){0.f,0.f,0.f,0.f};
            accS[i] = (f32x4){0.f,0.f,0.f,0.f};
            accT[i] = (f32x4){0.f,0.f,0.f,0.f};
        }
        #pragma unroll
        for (int ks = 0; ks < 4; ++ks) {
            int k0 = (ks << 5) + (kp << 3);
            bf16x8 bws = ldw8<PRE>(wW2, aw2, (0 * F + col) * F + k0);
            bf16x8 bwt = ldw8<PRE>(wW2, aw2, (1 * F + col) * F + k0);
            bf16x8 bwv = ldw8<PRE>(wW2, aw2, (2 * F + col) * F + k0);
            #pragma unroll
            for (int nt = 0; nt < 2; ++nt) {
                bf16x8 a = *(const bf16x8*)&SH[A3B + (nt * 16 + l15) * A3S + k0];
                accS[nt] = __builtin_amdgcn_mfma_f32_16x16x32_bf16(a, bws, accS[nt], 0, 0, 0);
                accT[nt] = __builtin_amdgcn_mfma_f32_16x16x32_bf16(a, bwt, accT[nt], 0, 0, 0);
                accA[nt] = __builtin_amdgcn_mfma_f32_16x16x32_bf16(a, bwv, accA[nt], 0, 0, 0);
            }
        }

        // ---- epilogue: v_new and s_new (residuals from bf16 LDS tiles) ----
        #pragma unroll
        for (int nt = 0; nt < 2; ++nt) {
            #pragma unroll
            for (int r = 0; r < 4; ++r) {
                int nl = nt * 16 + (kp << 2) + r;
                int n  = t * TILE + nl;
                float avv = accA[nt][r] + bvv;
                size_t base = ((size_t)n * F + col) * 3;
                #pragma unroll
                for (int c = 0; c < 3; ++c) {
                    float vres = bf2f(SH[A1B + (c * TILE + nl) * A1S + col]);
                    float uv   = bf2f(pU[c * 2 + nt][r]);
                    out[NF + base + c] = vres + avv * uv;
                }
                float sres = bf2f(SH[A2B + nl * A2S + col]);
                out[(size_t)n * F + col] = sres + (accS[nt][r] + bss) + (accT[nt][r] + bsv) * inr[nt][r];
            }
        }
    }
}

extern "C" void kernel_launch(void* const* d_in, const int* in_sizes, int n_in,
                              void* d_out, int out_size, void* d_ws, size_t ws_size,
                              hipStream_t stream) {
    (void)n_in; (void)out_size;
    const float* s   = (const float*)d_in[0];
    const float* v   = (const float*)d_in[1];
    const float* Uw  = (const float*)d_in[2];
    const float* Vw  = (const float*)d_in[3];
    const float* aw1 = (const float*)d_in[4];
    const float* ab1 = (const float*)d_in[5];
    const float* aw2 = (const float*)d_in[6];
    const float* ab2 = (const float*)d_in[7];
    float* out = (float*)d_out;
    int Ntot = in_sizes[0] / F;                 // 100000 (divisible by TILE=32)

    if (ws_size >= 114688u * sizeof(unsigned short)) {
        unsigned short* wbf = (unsigned short*)d_ws;
        hipLaunchKernelGGL(prep_w, dim3(112), dim3(256), 0, stream, Uw, Vw, aw1, aw2, wbf);
        hipLaunchKernelGGL((painn_main<true>), dim3(NBLK), dim3(NTHR), 0, stream,
                           s, v, Uw, Vw, aw1, ab1, aw2, ab2, wbf, out, Ntot);
    } else {
        hipLaunchKernelGGL((painn_main<false>), dim3(NBLK), dim3(NTHR), 0, stream,
                           s, v, Uw, Vw, aw1, ab1, aw2, ab2, (const unsigned short*)nullptr, out, Ntot);
    }
}